// Round 11
// baseline (788.527 us; speedup 1.0000x reference)
//
#include <hip/hip_runtime.h>
#include <math.h>

typedef __attribute__((ext_vector_type(4))) float f32x4;
typedef __attribute__((ext_vector_type(8))) short bf16x8;
typedef __attribute__((ext_vector_type(4))) unsigned short u16x4;
typedef __attribute__((ext_vector_type(8))) unsigned short u16x8;

__device__ __forceinline__ unsigned short f2bf(float f) {
  unsigned u = __builtin_bit_cast(unsigned, f);
  u += 0x7fffu + ((u >> 16) & 1u);
  return (unsigned short)(u >> 16);
}
__device__ __forceinline__ float bf2f(unsigned short s) {
  return __builtin_bit_cast(float, (unsigned)s << 16);
}
__device__ __forceinline__ float sigmoidf_(float x) { return 1.f / (1.f + __expf(-x)); }

// ---------------------------------------------------------------------------
// bf16-MFMA GEMM, 128xTN tile (TN=128 or 64), BK=32, 4 waves, double-buffered
// LDS + 1-deep register prefetch, bijective XCD swizzle (grid product %8==0).
// C[M,N] = A[M,K] @ B[N,K]^T (+bias).
// ACAT/BCAT: K-concat (1st ptr k<Ksplit, 2nd after). z-split: z>=zs -> "b" set.
// ABF16: A is bf16. OBF16: C bf16 (EPI 0/3).
// EPI 0: (val)*scale
// EPI 1: val + P0[off] + P1[off]
// EPI 2: (P2+P3+ce+sig(val)*(P1-ce))/3, ce=P0[row*256+(col&255)]
// EPI 3: val * P0[2*row+hi]                       (rw-scaled, bf16 out)
// EPI 4: val + P2[2*row]*P0[col] + P2[2*row+1]*P1[col]
// ---------------------------------------------------------------------------
template <int TN, int ACAT, int BCAT, int EPI, int ABF16, int OBF16>
__global__ __launch_bounds__(256) void gemm_k(
    const void* __restrict__ A1, const void* __restrict__ A1b, int lda1, long aZ,
    const void* __restrict__ A2, int lda2, int Ksplit,
    const float* __restrict__ B1, const float* __restrict__ B1b, int ldb1, long bZ,
    const float* __restrict__ B2, int ldb2,
    const float* __restrict__ bias1, const float* __restrict__ bias1b, long biasZ,
    const float* __restrict__ bias2,
    void* __restrict__ C, void* __restrict__ Cb, int ldc, long cZ,
    int K, int zs, float scale,
    const float* __restrict__ P0, const float* __restrict__ P1,
    const float* __restrict__ P2, const float* __restrict__ P3) {
  constexpr int NBI = TN / 32;
  __shared__ unsigned short As[2][128][32];
  __shared__ unsigned short Bs[2][TN][32];
  const int t = threadIdx.x;
  const int lane = t & 63;
  const int wave = t >> 6;
  const int wr = wave >> 1, wc = wave & 1;

  const unsigned gx = gridDim.x, gy = gridDim.y;
  unsigned L = blockIdx.x + gx * (blockIdx.y + gy * blockIdx.z);
  const unsigned nwg = gx * gy * gridDim.z;
  L = (L & 7u) * (nwg >> 3) + (L >> 3);
  const int bn = L % gx;
  const unsigned r1 = L / gx;
  const int bm = r1 % gy;
  const int z = r1 / gy;

  const bool hi = z >= zs;
  const int zz = hi ? z - zs : z;
  const char* Abase = (const char*)(hi ? A1b : A1) + (long)zz * aZ * (ABF16 ? 2 : 4);
  const float* Bbase = (hi ? B1b : B1) + (long)zz * bZ;
  const float* biasp = hi ? bias1b : bias1;
  char* Czc = (char*)(hi ? Cb : C) + (long)zz * cZ * (OBF16 ? 2 : 4);

  const int ar = t >> 3;
  const int bc = (t & 7) * 4;

  const int kIters = K >> 5;
  u16x4 Ra[4], Rb[NBI];

  auto loadT = [&](int kt) {
    const int k0 = kt << 5;
    const char* Ap; int ldA, kA;
    if (ACAT == 1 && k0 >= Ksplit) { Ap = (const char*)A2; ldA = lda2; kA = k0 - Ksplit; }
    else { Ap = Abase; ldA = lda1; kA = k0; }
    const float* Bp; int ldB, kB;
    if (BCAT == 1 && k0 >= Ksplit) { Bp = B2; ldB = ldb2; kB = k0 - Ksplit; }
    else { Bp = Bbase; ldB = ldb1; kB = k0; }
#pragma unroll
    for (int i = 0; i < 4; ++i) {
      const long aoff = ((long)bm * 128 + ar + 32 * i) * ldA + kA + bc;
      if (ABF16) {
        Ra[i] = *(const u16x4*)((const unsigned short*)Ap + aoff);
      } else {
        f32x4 v = *(const f32x4*)((const float*)Ap + aoff);
        u16x4 pk;
        pk[0] = f2bf(v[0]); pk[1] = f2bf(v[1]); pk[2] = f2bf(v[2]); pk[3] = f2bf(v[3]);
        Ra[i] = pk;
      }
    }
#pragma unroll
    for (int i = 0; i < NBI; ++i) {
      f32x4 bv = *(const f32x4*)(Bp + ((long)bn * TN + ar + 32 * i) * ldB + kB + bc);
      u16x4 bp;
      bp[0] = f2bf(bv[0]); bp[1] = f2bf(bv[1]); bp[2] = f2bf(bv[2]); bp[3] = f2bf(bv[3]);
      Rb[i] = bp;
    }
  };

  loadT(0);

  f32x4 acc[4][NBI] = {};
  int p = 0;
  for (int kt = 0; kt < kIters; ++kt) {
    __syncthreads();
#pragma unroll
    for (int i = 0; i < 4; ++i) *(u16x4*)&As[p][ar + 32 * i][bc] = Ra[i];
#pragma unroll
    for (int i = 0; i < NBI; ++i) *(u16x4*)&Bs[p][ar + 32 * i][bc] = Rb[i];
    if (kt + 1 < kIters) loadT(kt + 1);
    __syncthreads();

    bf16x8 af[4], bfr[NBI];
#pragma unroll
    for (int mi = 0; mi < 4; ++mi)
      af[mi] = *(const bf16x8*)&As[p][wr * 64 + mi * 16 + (lane & 15)][(lane >> 4) * 8];
#pragma unroll
    for (int ni = 0; ni < NBI; ++ni)
      bfr[ni] = *(const bf16x8*)&Bs[p][wc * (TN / 2) + ni * 16 + (lane & 15)][(lane >> 4) * 8];
#pragma unroll
    for (int mi = 0; mi < 4; ++mi)
#pragma unroll
      for (int ni = 0; ni < NBI; ++ni)
        acc[mi][ni] = __builtin_amdgcn_mfma_f32_16x16x32_bf16(af[mi], bfr[ni], acc[mi][ni], 0, 0, 0);
    p ^= 1;
  }

  const int colb = bn * TN + wc * (TN / 2);
  const int rowb = bm * 128 + wr * 64;
#pragma unroll
  for (int mi = 0; mi < 4; ++mi) {
#pragma unroll
    for (int ni = 0; ni < NBI; ++ni) {
      f32x4 v = acc[mi][ni];
      const int col = colb + ni * 16 + (lane & 15);
      const int row0 = rowb + mi * 16 + ((lane >> 4) << 2);
      float bsum = 0.f;
      if (biasp) bsum += biasp[zz * biasZ + col];
      if (bias2) bsum += bias2[col];
#pragma unroll
      for (int q = 0; q < 4; ++q) {
        const long row = row0 + q;
        const long off = row * ldc + col;
        const float val = v[q] + bsum;
        if (EPI == 0) {
          if (OBF16) ((unsigned short*)Czc)[off] = f2bf(val * scale);
          else       ((float*)Czc)[off] = val * scale;
        } else if (EPI == 1) {
          ((float*)Czc)[off] = val + P0[off] + P1[off];
        } else if (EPI == 2) {
          const float g = sigmoidf_(val);
          const float ce = P0[row * 256 + (col & 255)];
          const float ex = P1[off];
          ((float*)Czc)[off] = (P2[off] + P3[off] + ce + g * (ex - ce)) * (1.f / 3.f);
        } else if (EPI == 3) {
          ((unsigned short*)Czc)[off] = f2bf(val * P0[2 * row + (hi ? 1 : 0)]);
        } else {
          ((float*)Czc)[off] = val + P2[2 * row] * P0[col] + P2[2 * row + 1] * P1[col];
        }
      }
    }
  }
}

// 64x64 LDS-tiled transpose, z selects (in,out) pair. out[n][d] = in[d][n]
__global__ __launch_bounds__(256) void transpose_k(const float* __restrict__ in0,
                                                   float* __restrict__ out0,
                                                   const float* __restrict__ in1,
                                                   float* __restrict__ out1, int n) {
  __shared__ float tile[64][65];
  const float* in = blockIdx.z ? in1 : in0;
  float* out = blockIdx.z ? out1 : out0;
  const int tr = blockIdx.y, tc = blockIdx.x, t = threadIdx.x;
#pragma unroll
  for (int it = 0; it < 16; ++it) {
    int idx = t + 256 * it;
    int r = idx >> 6, c = idx & 63;
    tile[r][c] = in[(long)(tr * 64 + r) * n + tc * 64 + c];
  }
  __syncthreads();
#pragma unroll
  for (int it = 0; it < 16; ++it) {
    int idx = t + 256 * it;
    int rr = idx >> 6, cc = idx & 63;
    out[(long)(tc * 64 + rr) * n + tr * 64 + cc] = tile[cc][rr];
  }
}

// LSTM elementwise + fused router (block == one batch row b)
__global__ __launch_bounds__(256) void lstm_k(const float* __restrict__ gates,
                                              const float* __restrict__ c_in,
                                              const float* __restrict__ Wr,
                                              const float* __restrict__ br,
                                              float* __restrict__ c_out,
                                              float* __restrict__ h_ws,
                                              float* __restrict__ h_out,
                                              float* __restrict__ rw) {
  const int b = blockIdx.x, t = threadIdx.x;
  const long base = (long)b * 1024 + t * 4;
  const float* gb = gates + (long)b * 4096 + t * 4;
  f32x4 gi = *(const f32x4*)(gb);
  f32x4 gf = *(const f32x4*)(gb + 1024);
  f32x4 gg = *(const f32x4*)(gb + 2048);
  f32x4 go = *(const f32x4*)(gb + 3072);
  f32x4 cv = *(const f32x4*)(c_in + base);
  f32x4 cn, hv;
#pragma unroll
  for (int q = 0; q < 4; ++q) {
    float cc = sigmoidf_(gf[q]) * cv[q] + sigmoidf_(gi[q]) * tanhf(gg[q]);
    cn[q] = cc;
    hv[q] = sigmoidf_(go[q]) * tanhf(cc);
  }
  *(f32x4*)(c_out + base) = cn;
  *(f32x4*)(h_ws + base) = hv;
  *(f32x4*)(h_out + base) = hv;
  f32x4 w0 = *(const f32x4*)(Wr + t * 4);
  f32x4 w1 = *(const f32x4*)(Wr + 1024 + t * 4);
  float a0 = hv[0] * w0[0] + hv[1] * w0[1] + hv[2] * w0[2] + hv[3] * w0[3];
  float a1 = hv[0] * w1[0] + hv[1] * w1[1] + hv[2] * w1[2] + hv[3] * w1[3];
#pragma unroll
  for (int m = 32; m >= 1; m >>= 1) {
    a0 += __shfl_xor(a0, m);
    a1 += __shfl_xor(a1, m);
  }
  __shared__ float red[8];
  if ((t & 63) == 0) { red[t >> 6] = a0; red[4 + (t >> 6)] = a1; }
  __syncthreads();
  if (t == 0) {
    float z0 = red[0] + red[1] + red[2] + red[3] + br[0];
    float z1 = red[4] + red[5] + red[6] + red[7] + br[1];
    float mx = fmaxf(z0, z1);
    float e0 = __expf(z0 - mx), e1 = __expf(z1 - mx);
    float s = e0 + e1;
    rw[2 * b] = e0 / s;
    rw[2 * b + 1] = e1 / s;
  }
}

// ---------------------------------------------------------------------------
// Attention scores + softmax + ts. Block = one (b, side), 256 threads,
// XCD-swizzled grid. CHANGE vs round 10: qt staged as **f32** in LDS,
// [kq][h] f32x4 with pitch 36 floats. Read pattern (per u,hh: 8 distinct
// f32x4 at bank-stride 4, broadcast x8 lanes) is conflict-free, and the
// hot loop loses all bf2f unpack VALU (72 -> 40 ops per 4 K-floats),
// cutting both VALU time and live registers (round 10: VGPR=124).
// ---------------------------------------------------------------------------
__global__ __launch_bounds__(256) void scores9_k(
    const float* __restrict__ memK, const float* __restrict__ extK,
    const float* __restrict__ hl,
    const unsigned short* __restrict__ qtS, const unsigned short* __restrict__ qtE,
    float* __restrict__ P_g, float* __restrict__ ts) {
  const int NB = 2048, H = 1024;
  __shared__ float qtf[256 * 36];  // [kq 0..255][pitch 36 f32: h*4]
  __shared__ float S_lds[32][8];
  unsigned flat = blockIdx.x + gridDim.x * blockIdx.y;  // 0..4095
  flat = (flat & 7u) * 512u + (flat >> 3);              // bijective XCD swizzle
  const int b = flat & 2047;
  const bool self = (flat >> 11) == 0;
  const int t = threadIdx.x;

  // stage qt: global [h][k] bf16 -> LDS [kq][h] f32x4
  {
    const unsigned short* qtb = (self ? qtS : qtE) + (long)b * 8192;
#pragma unroll
    for (int i = 0; i < 4; ++i) {
      const int chunk = t + 256 * i;      // 1024 chunks of u16x8
      const int hh = chunk >> 7;
      const int pos = (chunk & 127) * 8;  // k position
      u16x8 qv = *(const u16x8*)(qtb + hh * 1024 + pos);
      const int kq0 = pos >> 2;
      f32x4 a, bb;
      a[0] = bf2f(qv[0]); a[1] = bf2f(qv[1]); a[2] = bf2f(qv[2]); a[3] = bf2f(qv[3]);
      bb[0] = bf2f(qv[4]); bb[1] = bf2f(qv[5]); bb[2] = bf2f(qv[6]); bb[3] = bf2f(qv[7]);
      *(f32x4*)&qtf[kq0 * 36 + hh * 4] = a;
      *(f32x4*)&qtf[(kq0 + 1) * 36 + hh * 4] = bb;
    }
  }
  __syncthreads();

  const int r = t >> 3, sub = t & 7;
  const float* Kr = self ? ((r < 31) ? memK + ((long)(r + 1) * NB + b) * H : hl + (long)b * H)
                         : extK + ((long)r * NB + b) * H;
  float acc[8] = {};
#pragma unroll
  for (int i = 0; i < 32; i += 4) {
    f32x4 kv[4];
#pragma unroll
    for (int u = 0; u < 4; ++u) kv[u] = *(const f32x4*)(Kr + ((i + u) * 8 + sub) * 4);
#pragma unroll
    for (int u = 0; u < 4; ++u) {
      const float* qp = &qtf[((i + u) * 8 + sub) * 36];
#pragma unroll
      for (int hh = 0; hh < 8; ++hh) {
        f32x4 q = *(const f32x4*)(qp + hh * 4);
        acc[hh] += kv[u][0] * q[0] + kv[u][1] * q[1] + kv[u][2] * q[2] + kv[u][3] * q[3];
      }
    }
  }
#pragma unroll
  for (int hh = 0; hh < 8; ++hh) {
    acc[hh] += __shfl_xor(acc[hh], 1);
    acc[hh] += __shfl_xor(acc[hh], 2);
    acc[hh] += __shfl_xor(acc[hh], 4);
  }
  if (sub == 0) {
#pragma unroll
    for (int hh = 0; hh < 8; ++hh) S_lds[r][hh] = acc[hh];
  }
  __syncthreads();
  {
    const int l = t & 31, hh = t >> 5;
    float Sv = S_lds[l][hh];
    float mx = Sv;
#pragma unroll
    for (int m = 16; m >= 1; m >>= 1) mx = fmaxf(mx, __shfl_xor(mx, m, 32));
    float pr = __expf(Sv - mx);
    float su = pr;
#pragma unroll
    for (int m = 16; m >= 1; m >>= 1) su += __shfl_xor(su, m, 32);
    P_g[((long)b * 2 + (self ? 0 : 1)) * 256 + l * 8 + hh] = pr / su;
  }
  if (self) {
    const float* Kb = memK + (long)b * H + 4 * t;
    f32x4 a = {};
#pragma unroll
    for (int l = 0; l < 31; ++l) a += *(const f32x4*)(Kb + (long)(l + 1) * NB * H);
    a += *(const f32x4*)(hl + (long)b * H + 4 * t);
    *(f32x4*)(ts + (long)b * H + 4 * t) = a * (1.f / 32.f);
  }
}

// ---------------------------------------------------------------------------
// Attention V-mix. Block = one (b, side), 256 threads, 1 KB LDS. 2-deep
// l-unroll keeps live state to acc(32) + vv(8) ~ 60 VGPR. Per instruction
// the block reads one contiguous 4 KB V row. Coalesced bf16 stores.
// ---------------------------------------------------------------------------
__global__ __launch_bounds__(256) void mix8_k(
    const float* __restrict__ memV, const float* __restrict__ extV,
    const float* __restrict__ hl,
    const float* __restrict__ P_g,
    unsigned short* __restrict__ mixS, unsigned short* __restrict__ mixE) {
  const int NB = 2048, H = 1024;
  __shared__ float P_lds[256];
  unsigned flat = blockIdx.x + gridDim.x * blockIdx.y;
  flat = (flat & 7u) * 512u + (flat >> 3);
  const int b = flat & 2047;
  const bool self = (flat >> 11) == 0;
  const int t = threadIdx.x;

  P_lds[t] = P_g[((long)b * 2 + (self ? 0 : 1)) * 256 + t];
  __syncthreads();

  const float* Vbase = (self ? memV + (long)NB * H : extV) + (long)b * H + 4 * t;
  const float* hlp = hl + (long)b * H + 4 * t;
  f32x4 acc[8] = {};
#pragma unroll
  for (int l = 0; l < 32; l += 2) {
    f32x4 vv0 = *(const f32x4*)(Vbase + (long)l * NB * H);
    f32x4 vv1 = *(const f32x4*)((self && l + 1 == 31) ? hlp
                                                      : Vbase + (long)(l + 1) * NB * H);
    const float* Pl0 = &P_lds[l * 8];
    const float* Pl1 = &P_lds[(l + 1) * 8];
#pragma unroll
    for (int hh = 0; hh < 8; ++hh) acc[hh] += Pl0[hh] * vv0;
#pragma unroll
    for (int hh = 0; hh < 8; ++hh) acc[hh] += Pl1[hh] * vv1;
  }
  unsigned short* mixp = (self ? mixS : mixE) + (long)b * 8192;
#pragma unroll
  for (int hh = 0; hh < 8; ++hh) {
    u16x4 pk;
    pk[0] = f2bf(acc[hh][0]); pk[1] = f2bf(acc[hh][1]);
    pk[2] = f2bf(acc[hh][2]); pk[3] = f2bf(acc[hh][3]);
    *(u16x4*)(mixp + hh * 1024 + 4 * t) = pk;
  }
}

extern "C" void kernel_launch(void* const* d_in, const int* in_sizes, int n_in,
                              void* d_out, int out_size, void* d_ws, size_t ws_size,
                              hipStream_t stream) {
  const float* x    = (const float*)d_in[0];
  const float* h    = (const float*)d_in[1];
  const float* c    = (const float*)d_in[2];
  const float* memK = (const float*)d_in[3];
  const float* memV = (const float*)d_in[4];
  const float* extK = (const float*)d_in[5];
  const float* extV = (const float*)d_in[6];
  const float* W_ih = (const float*)d_in[7];
  const float* W_hh = (const float*)d_in[8];
  const float* b_ih = (const float*)d_in[9];
  const float* b_hh = (const float*)d_in[10];
  const float* sWq = (const float*)d_in[11];
  const float* sbq = (const float*)d_in[12];
  const float* sWk = (const float*)d_in[13];
  const float* sWv = (const float*)d_in[15];
  const float* sbv = (const float*)d_in[16];
  const float* sWo = (const float*)d_in[17];
  const float* sbo = (const float*)d_in[18];
  const float* cWq = (const float*)d_in[19];
  const float* cbq = (const float*)d_in[20];
  const float* cWk = (const float*)d_in[21];
  const float* cWv = (const float*)d_in[23];
  const float* cbv = (const float*)d_in[24];
  const float* cWo = (const float*)d_in[25];
  const float* cbo = (const float*)d_in[26];
  const float* Wres = (const float*)d_in[27];
  const float* bres = (const float*)d_in[28];
  const float* Wrout = (const float*)d_in[29];
  const float* brout = (const float*)d_in[30];
  const float* Wcomp = (const float*)d_in[31];
  const float* bcomp = (const float*)d_in[32];
  const float* Wexp = (const float*)d_in[33];
  const float* bexp = (const float*)d_in[34];
  const float* Wgate = (const float*)d_in[35];
  const float* bgate = (const float*)d_in[36];
  (void)in_sizes; (void)n_in; (void)out_size; (void)ws_size;

  float* out = (float*)d_out;
  float* w = (float*)d_ws;
  const long M1 = 1024 * 1024;
  float* gates   = w;            // [2048,4096] f32 ; dead after lstm_k
  float* P_g     = w;            // [2048,2,256] f32 (4MB) reuses gates
  float* hl      = w + 8 * M1;   // [2048,1024] f32
  unsigned short* qsS = (unsigned short*)(w + 10 * M1);  // [2048,1024] bf16
  unsigned short* qsE = (unsigned short*)(w + 12 * M1);
  float* wkTs    = w + 14 * M1;  // [1024,1024] f32
  float* wkTc    = w + 15 * M1;
  unsigned short* qtS = (unsigned short*)(w + 16 * M1);  // [2048,8192] bf16
  unsigned short* qtE = (unsigned short*)(w + 32 * M1);
  unsigned short* mixS = (unsigned short*)(w + 48 * M1); // [2048,8192] bf16
  unsigned short* mixE = (unsigned short*)(w + 64 * M1);
  float* ts      = w + 80 * M1;  // [2048,1024] f32
  unsigned short* attnS = (unsigned short*)(w + 82 * M1);  // [2048,1024] bf16 (rw-scaled)
  unsigned short* attnE = (unsigned short*)(w + 84 * M1);
  float* rw      = w + 90 * M1;  // [2048,2]
  float* rattn   = w + 91 * M1;  // [2048,1024] f32
  float* routed  = w + 93 * M1;
  float* comp    = w + 95 * M1;  // [2048,256] f32
  float* expd    = w + 96 * M1;

  float* hFinal_out = out;
  float* hl_out     = out + 2 * M1;
  float* cn_out     = out + 4 * M1;

  const float scaleq = 0.08838834764831845f;  // 1/sqrt(128)
  const int ZBIG = 1 << 30;
  dim3 blk(256);
  const float* nf = nullptr;

  // gates = x@W_ih^T + h@W_hh^T + b_ih + b_hh
  gemm_k<128, 1, 1, 0, 0, 0><<<dim3(32, 16, 1), blk, 0, stream>>>(
      x, nullptr, 1024, 0, h, 1024, 1024,
      W_ih, nf, 1024, 0, W_hh, 1024,
      b_ih, nf, 0, b_hh,
      gates, nullptr, 4096, 0,
      2048, ZBIG, 1.f, nf, nf, nf, nf);

  transpose_k<<<dim3(16, 16, 2), blk, 0, stream>>>(sWk, wkTs, cWk, wkTc, 1024);

  lstm_k<<<2048, blk, 0, stream>>>(gates, c, Wrout, brout, cn_out, hl, hl_out, rw);

  // qs (z=0 self, z=1 ext), scaled, bf16 out
  gemm_k<128, 0, 0, 0, 0, 1><<<dim3(8, 16, 2), blk, 0, stream>>>(
      hl, hl, 1024, 0, nullptr, 0, 0,
      sWq, cWq, 1024, 0, nf, 0,
      sbq, cbq, 0, nf,
      qsS, qsE, 1024, 0,
      1024, 1, scaleq, nf, nf, nf, nf);

  // qt[b,h,k] = sum_d qs[b,h*128+d]*WkT[k,h*128+d]; z: 0-7 self, 8-15 ext
  gemm_k<128, 0, 0, 0, 1, 1><<<dim3(8, 16, 16), blk, 0, stream>>>(
      qsS, qsE, 1024, 128, nullptr, 0, 0,
      wkTs, wkTc, 1024, 128, nf, 0,
      nf, nf, 0, nf,
      qtS, qtE, 8192, 1024,
      128, 8, 1.f, nf, nf, nf, nf);

  // attention: lean streaming kernels
  scores9_k<<<dim3(2048, 2), blk, 0, stream>>>(memK, extK, hl, qtS, qtE, P_g, ts);
  mix8_k<<<dim3(2048, 2), blk, 0, stream>>>(memV, extV, hl, P_g, mixS, mixE);

  // attn'[b,h*128+d] = (mix@Wv_h^T + bv) * rw ; z: 0-7 self, 8-15 ext; bf16
  gemm_k<64, 0, 0, 3, 1, 1><<<dim3(2, 16, 16), blk, 0, stream>>>(
      mixS, mixE, 8192, 1024, nullptr, 0, 0,
      sWv, cWv, 1024, 131072, nf, 0,
      sbv, cbv, 128, nf,
      attnS, attnE, 1024, 128,
      1024, 8, 1.f, rw, nf, nf, nf);

  // rattn = [w0*attnS | w1*attnE] @ [sWo;cWo]^T + w0*sbo + w1*cbo
  gemm_k<64, 1, 1, 4, 1, 0><<<dim3(16, 16, 1), blk, 0, stream>>>(
      attnS, nullptr, 1024, 0, attnE, 1024, 1024,
      sWo, nf, 1024, 0, cWo, 1024,
      nf, nf, 0, nf,
      rattn, nullptr, 1024, 0,
      2048, ZBIG, 1.f, sbo, cbo, rw, nf);

  // routed = h_lstm + rattn + rattn@Wres^T + bres
  gemm_k<64, 0, 0, 1, 0, 0><<<dim3(16, 16, 1), blk, 0, stream>>>(
      rattn, nullptr, 1024, 0, nullptr, 0, 0,
      Wres, nf, 1024, 0, nf, 0,
      bres, nf, 0, nf,
      routed, nullptr, 1024, 0,
      1024, ZBIG, 1.f, hl, rattn, nf, nf);

  // compressed / expanded
  gemm_k<64, 0, 0, 0, 0, 0><<<dim3(4, 16, 1), blk, 0, stream>>>(
      ts, nullptr, 1024, 0, nullptr, 0, 0,
      Wcomp, nf, 1024, 0, nf, 0,
      bcomp, nf, 0, nf,
      comp, nullptr, 256, 0,
      1024, ZBIG, 1.f, nf, nf, nf, nf);
  gemm_k<64, 0, 0, 0, 0, 0><<<dim3(16, 16, 1), blk, 0, stream>>>(
      comp, nullptr, 256, 0, nullptr, 0, 0,
      Wexp, nf, 256, 0, nf, 0,
      bexp, nf, 0, nf,
      expd, nullptr, 1024, 0,
      256, ZBIG, 1.f, nf, nf, nf, nf);

  // gate GEMM (A = [x | routed]) + fused final epilogue
  gemm_k<64, 1, 0, 2, 0, 0><<<dim3(16, 16, 1), blk, 0, stream>>>(
      x, nullptr, 1024, 0, routed, 1024, 1024,
      Wgate, nf, 2048, 0, nf, 0,
      bgate, nf, 0, nf,
      hFinal_out, nullptr, 1024, 0,
      2048, ZBIG, 1.f, comp, expd, hl, routed);
}

// Round 12
// 660.833 us; speedup vs baseline: 1.1932x; 1.1932x over previous
//
#include <hip/hip_runtime.h>
#include <math.h>

typedef __attribute__((ext_vector_type(4))) float f32x4;
typedef __attribute__((ext_vector_type(8))) short bf16x8;
typedef __attribute__((ext_vector_type(4))) unsigned short u16x4;
typedef __attribute__((ext_vector_type(8))) unsigned short u16x8;

__device__ __forceinline__ unsigned short f2bf(float f) {
  unsigned u = __builtin_bit_cast(unsigned, f);
  u += 0x7fffu + ((u >> 16) & 1u);
  return (unsigned short)(u >> 16);
}
__device__ __forceinline__ float bf2f(unsigned short s) {
  return __builtin_bit_cast(float, (unsigned)s << 16);
}
__device__ __forceinline__ float sigmoidf_(float x) { return 1.f / (1.f + __expf(-x)); }

// ---------------------------------------------------------------------------
// Batched fp32 -> bf16 conversion. Each job converted in 2048-elem blocks.
// ---------------------------------------------------------------------------
struct CJob { const float* s; unsigned short* d; int nblk; };
struct CJobs { CJob j[14]; };

__global__ __launch_bounds__(256) void conv_k(CJobs jb) {
  int b = blockIdx.x;
  int i = 0;
  while (b >= jb.j[i].nblk) { b -= jb.j[i].nblk; ++i; }
  const long base = (long)b * 2048 + threadIdx.x * 8;
  f32x4 a = *(const f32x4*)(jb.j[i].s + base);
  f32x4 c = *(const f32x4*)(jb.j[i].s + base + 4);
  u16x8 o;
  o[0] = f2bf(a[0]); o[1] = f2bf(a[1]); o[2] = f2bf(a[2]); o[3] = f2bf(a[3]);
  o[4] = f2bf(c[0]); o[5] = f2bf(c[1]); o[6] = f2bf(c[2]); o[7] = f2bf(c[3]);
  *(u16x8*)(jb.j[i].d + base) = o;
}

// ---------------------------------------------------------------------------
// bf16-MFMA GEMM, 128xTN tile (TN=128 or 64), BK=32, 4 waves, double-buffered
// LDS + 1-deep register prefetch, bijective XCD swizzle (grid product %8==0).
// C[M,N] = A[M,K] @ B[N,K]^T (+bias).
// ACAT/BCAT: K-concat. z-split: z>=zs -> "b" pointer set.
// ABF16/BBF16: operand dtype. OBF16: C bf16 (EPI 0/3).
// EPI 0: val*scale ; 1: val+P0+P1 (f32 C; if Cb, also bf16 mirror to Cb)
// EPI 2: (P2+P3+ce+sig(val)*(P1-ce))/3, ce=P0[row*256+(col&255)]
// EPI 3: val*P0[2*row+hi] (bf16) ; EPI 4: val+P2[2*row]*P0[col]+P2[2*row+1]*P1[col]
// ---------------------------------------------------------------------------
template <int TN, int ACAT, int BCAT, int EPI, int ABF16, int BBF16, int OBF16>
__global__ __launch_bounds__(256) void gemm_k(
    const void* __restrict__ A1, const void* __restrict__ A1b, int lda1, long aZ,
    const void* __restrict__ A2, int lda2, int Ksplit,
    const void* __restrict__ B1, const void* __restrict__ B1b, int ldb1, long bZ,
    const void* __restrict__ B2, int ldb2,
    const float* __restrict__ bias1, const float* __restrict__ bias1b, long biasZ,
    const float* __restrict__ bias2,
    void* __restrict__ C, void* __restrict__ Cb, int ldc, long cZ,
    int K, int zs, float scale,
    const float* __restrict__ P0, const float* __restrict__ P1,
    const float* __restrict__ P2, const float* __restrict__ P3) {
  constexpr int NBI = TN / 32;
  __shared__ unsigned short As[2][128][32];
  __shared__ unsigned short Bs[2][TN][32];
  const int t = threadIdx.x;
  const int lane = t & 63;
  const int wave = t >> 6;
  const int wr = wave >> 1, wc = wave & 1;

  const unsigned gx = gridDim.x, gy = gridDim.y;
  unsigned L = blockIdx.x + gx * (blockIdx.y + gy * blockIdx.z);
  const unsigned nwg = gx * gy * gridDim.z;
  L = (L & 7u) * (nwg >> 3) + (L >> 3);
  const int bn = L % gx;
  const unsigned r1 = L / gx;
  const int bm = r1 % gy;
  const int z = r1 / gy;

  const bool hi = z >= zs;
  const int zz = hi ? z - zs : z;
  const char* Abase = (const char*)(hi ? A1b : A1) + (long)zz * aZ * (ABF16 ? 2 : 4);
  const char* Bbase = (const char*)(hi ? B1b : B1) + (long)zz * bZ * (BBF16 ? 2 : 4);
  const float* biasp = hi ? bias1b : bias1;
  char* Czc = (char*)(hi ? Cb : C) + (long)zz * cZ * (OBF16 ? 2 : 4);

  const int ar = t >> 3;
  const int bc = (t & 7) * 4;

  const int kIters = K >> 5;
  u16x4 Ra[4], Rb[NBI];

  auto loadT = [&](int kt) {
    const int k0 = kt << 5;
    const char* Ap; int ldA, kA;
    if (ACAT == 1 && k0 >= Ksplit) { Ap = (const char*)A2; ldA = lda2; kA = k0 - Ksplit; }
    else { Ap = Abase; ldA = lda1; kA = k0; }
    const char* Bp; int ldB, kB;
    if (BCAT == 1 && k0 >= Ksplit) { Bp = (const char*)B2; ldB = ldb2; kB = k0 - Ksplit; }
    else { Bp = Bbase; ldB = ldb1; kB = k0; }
#pragma unroll
    for (int i = 0; i < 4; ++i) {
      const long aoff = ((long)bm * 128 + ar + 32 * i) * ldA + kA + bc;
      if (ABF16) {
        Ra[i] = *(const u16x4*)((const unsigned short*)Ap + aoff);
      } else {
        f32x4 v = *(const f32x4*)((const float*)Ap + aoff);
        u16x4 pk;
        pk[0] = f2bf(v[0]); pk[1] = f2bf(v[1]); pk[2] = f2bf(v[2]); pk[3] = f2bf(v[3]);
        Ra[i] = pk;
      }
    }
#pragma unroll
    for (int i = 0; i < NBI; ++i) {
      const long boff = ((long)bn * TN + ar + 32 * i) * ldB + kB + bc;
      if (BBF16) {
        Rb[i] = *(const u16x4*)((const unsigned short*)Bp + boff);
      } else {
        f32x4 bv = *(const f32x4*)((const float*)Bp + boff);
        u16x4 bp;
        bp[0] = f2bf(bv[0]); bp[1] = f2bf(bv[1]); bp[2] = f2bf(bv[2]); bp[3] = f2bf(bv[3]);
        Rb[i] = bp;
      }
    }
  };

  loadT(0);

  f32x4 acc[4][NBI] = {};
  int p = 0;
  for (int kt = 0; kt < kIters; ++kt) {
    __syncthreads();
#pragma unroll
    for (int i = 0; i < 4; ++i) *(u16x4*)&As[p][ar + 32 * i][bc] = Ra[i];
#pragma unroll
    for (int i = 0; i < NBI; ++i) *(u16x4*)&Bs[p][ar + 32 * i][bc] = Rb[i];
    if (kt + 1 < kIters) loadT(kt + 1);
    __syncthreads();

    bf16x8 af[4], bfr[NBI];
#pragma unroll
    for (int mi = 0; mi < 4; ++mi)
      af[mi] = *(const bf16x8*)&As[p][wr * 64 + mi * 16 + (lane & 15)][(lane >> 4) * 8];
#pragma unroll
    for (int ni = 0; ni < NBI; ++ni)
      bfr[ni] = *(const bf16x8*)&Bs[p][wc * (TN / 2) + ni * 16 + (lane & 15)][(lane >> 4) * 8];
#pragma unroll
    for (int mi = 0; mi < 4; ++mi)
#pragma unroll
      for (int ni = 0; ni < NBI; ++ni)
        acc[mi][ni] = __builtin_amdgcn_mfma_f32_16x16x32_bf16(af[mi], bfr[ni], acc[mi][ni], 0, 0, 0);
    p ^= 1;
  }

  const int colb = bn * TN + wc * (TN / 2);
  const int rowb = bm * 128 + wr * 64;
#pragma unroll
  for (int mi = 0; mi < 4; ++mi) {
#pragma unroll
    for (int ni = 0; ni < NBI; ++ni) {
      f32x4 v = acc[mi][ni];
      const int col = colb + ni * 16 + (lane & 15);
      const int row0 = rowb + mi * 16 + ((lane >> 4) << 2);
      float bsum = 0.f;
      if (biasp) bsum += biasp[zz * biasZ + col];
      if (bias2) bsum += bias2[col];
#pragma unroll
      for (int q = 0; q < 4; ++q) {
        const long row = row0 + q;
        const long off = row * ldc + col;
        const float val = v[q] + bsum;
        if (EPI == 0) {
          if (OBF16) ((unsigned short*)Czc)[off] = f2bf(val * scale);
          else       ((float*)Czc)[off] = val * scale;
        } else if (EPI == 1) {
          const float r2 = val + P0[off] + P1[off];
          ((float*)Czc)[off] = r2;
          if (Cb) ((unsigned short*)Cb)[off] = f2bf(r2);
        } else if (EPI == 2) {
          const float g = sigmoidf_(val);
          const float ce = P0[row * 256 + (col & 255)];
          const float ex = P1[off];
          ((float*)Czc)[off] = (P2[off] + P3[off] + ce + g * (ex - ce)) * (1.f / 3.f);
        } else if (EPI == 3) {
          ((unsigned short*)Czc)[off] = f2bf(val * P0[2 * row + (hi ? 1 : 0)]);
        } else {
          ((float*)Czc)[off] = val + P2[2 * row] * P0[col] + P2[2 * row + 1] * P1[col];
        }
      }
    }
  }
}

// 64x64 LDS-tiled transpose, f32 in -> bf16 out. out[n][d] = bf16(in[d][n])
__global__ __launch_bounds__(256) void transpose_k(const float* __restrict__ in0,
                                                   unsigned short* __restrict__ out0,
                                                   const float* __restrict__ in1,
                                                   unsigned short* __restrict__ out1, int n) {
  __shared__ float tile[64][65];
  const float* in = blockIdx.z ? in1 : in0;
  unsigned short* out = blockIdx.z ? out1 : out0;
  const int tr = blockIdx.y, tc = blockIdx.x, t = threadIdx.x;
#pragma unroll
  for (int it = 0; it < 16; ++it) {
    int idx = t + 256 * it;
    int r = idx >> 6, c = idx & 63;
    tile[r][c] = in[(long)(tr * 64 + r) * n + tc * 64 + c];
  }
  __syncthreads();
#pragma unroll
  for (int it = 0; it < 16; ++it) {
    int idx = t + 256 * it;
    int rr = idx >> 6, cc = idx & 63;
    out[(long)(tc * 64 + rr) * n + tr * 64 + cc] = f2bf(tile[cc][rr]);
  }
}

// LSTM elementwise + fused router; emits hl in f32 (ws+out) and bf16 (hlb)
__global__ __launch_bounds__(256) void lstm_k(const float* __restrict__ gates,
                                              const float* __restrict__ c_in,
                                              const float* __restrict__ Wr,
                                              const float* __restrict__ br,
                                              float* __restrict__ c_out,
                                              float* __restrict__ h_ws,
                                              float* __restrict__ h_out,
                                              unsigned short* __restrict__ hlb,
                                              float* __restrict__ rw) {
  const int b = blockIdx.x, t = threadIdx.x;
  const long base = (long)b * 1024 + t * 4;
  const float* gb = gates + (long)b * 4096 + t * 4;
  f32x4 gi = *(const f32x4*)(gb);
  f32x4 gf = *(const f32x4*)(gb + 1024);
  f32x4 gg = *(const f32x4*)(gb + 2048);
  f32x4 go = *(const f32x4*)(gb + 3072);
  f32x4 cv = *(const f32x4*)(c_in + base);
  f32x4 cn, hv;
#pragma unroll
  for (int q = 0; q < 4; ++q) {
    float cc = sigmoidf_(gf[q]) * cv[q] + sigmoidf_(gi[q]) * tanhf(gg[q]);
    cn[q] = cc;
    hv[q] = sigmoidf_(go[q]) * tanhf(cc);
  }
  *(f32x4*)(c_out + base) = cn;
  *(f32x4*)(h_ws + base) = hv;
  *(f32x4*)(h_out + base) = hv;
  u16x4 hp;
  hp[0] = f2bf(hv[0]); hp[1] = f2bf(hv[1]); hp[2] = f2bf(hv[2]); hp[3] = f2bf(hv[3]);
  *(u16x4*)(hlb + base) = hp;
  f32x4 w0 = *(const f32x4*)(Wr + t * 4);
  f32x4 w1 = *(const f32x4*)(Wr + 1024 + t * 4);
  float a0 = hv[0] * w0[0] + hv[1] * w0[1] + hv[2] * w0[2] + hv[3] * w0[3];
  float a1 = hv[0] * w1[0] + hv[1] * w1[1] + hv[2] * w1[2] + hv[3] * w1[3];
#pragma unroll
  for (int m = 32; m >= 1; m >>= 1) {
    a0 += __shfl_xor(a0, m);
    a1 += __shfl_xor(a1, m);
  }
  __shared__ float red[8];
  if ((t & 63) == 0) { red[t >> 6] = a0; red[4 + (t >> 6)] = a1; }
  __syncthreads();
  if (t == 0) {
    float z0 = red[0] + red[1] + red[2] + red[3] + br[0];
    float z1 = red[4] + red[5] + red[6] + red[7] + br[1];
    float mx = fmaxf(z0, z1);
    float e0 = __expf(z0 - mx), e1 = __expf(z1 - mx);
    float s = e0 + e1;
    rw[2 * b] = e0 / s;
    rw[2 * b + 1] = e1 / s;
  }
}

// ---------------------------------------------------------------------------
// Attention scores + softmax + ts (unchanged from round 11).
// ---------------------------------------------------------------------------
__global__ __launch_bounds__(256) void scores9_k(
    const float* __restrict__ memK, const float* __restrict__ extK,
    const float* __restrict__ hl,
    const unsigned short* __restrict__ qtS, const unsigned short* __restrict__ qtE,
    float* __restrict__ P_g, float* __restrict__ ts) {
  const int NB = 2048, H = 1024;
  __shared__ float qtf[256 * 36];
  __shared__ float S_lds[32][8];
  unsigned flat = blockIdx.x + gridDim.x * blockIdx.y;
  flat = (flat & 7u) * 512u + (flat >> 3);
  const int b = flat & 2047;
  const bool self = (flat >> 11) == 0;
  const int t = threadIdx.x;

  {
    const unsigned short* qtb = (self ? qtS : qtE) + (long)b * 8192;
#pragma unroll
    for (int i = 0; i < 4; ++i) {
      const int chunk = t + 256 * i;
      const int hh = chunk >> 7;
      const int pos = (chunk & 127) * 8;
      u16x8 qv = *(const u16x8*)(qtb + hh * 1024 + pos);
      const int kq0 = pos >> 2;
      f32x4 a, bb;
      a[0] = bf2f(qv[0]); a[1] = bf2f(qv[1]); a[2] = bf2f(qv[2]); a[3] = bf2f(qv[3]);
      bb[0] = bf2f(qv[4]); bb[1] = bf2f(qv[5]); bb[2] = bf2f(qv[6]); bb[3] = bf2f(qv[7]);
      *(f32x4*)&qtf[kq0 * 36 + hh * 4] = a;
      *(f32x4*)&qtf[(kq0 + 1) * 36 + hh * 4] = bb;
    }
  }
  __syncthreads();

  const int r = t >> 3, sub = t & 7;
  const float* Kr = self ? ((r < 31) ? memK + ((long)(r + 1) * NB + b) * H : hl + (long)b * H)
                         : extK + ((long)r * NB + b) * H;
  float acc[8] = {};
#pragma unroll
  for (int i = 0; i < 32; i += 4) {
    f32x4 kv[4];
#pragma unroll
    for (int u = 0; u < 4; ++u) kv[u] = *(const f32x4*)(Kr + ((i + u) * 8 + sub) * 4);
#pragma unroll
    for (int u = 0; u < 4; ++u) {
      const float* qp = &qtf[((i + u) * 8 + sub) * 36];
#pragma unroll
      for (int hh = 0; hh < 8; ++hh) {
        f32x4 q = *(const f32x4*)(qp + hh * 4);
        acc[hh] += kv[u][0] * q[0] + kv[u][1] * q[1] + kv[u][2] * q[2] + kv[u][3] * q[3];
      }
    }
  }
#pragma unroll
  for (int hh = 0; hh < 8; ++hh) {
    acc[hh] += __shfl_xor(acc[hh], 1);
    acc[hh] += __shfl_xor(acc[hh], 2);
    acc[hh] += __shfl_xor(acc[hh], 4);
  }
  if (sub == 0) {
#pragma unroll
    for (int hh = 0; hh < 8; ++hh) S_lds[r][hh] = acc[hh];
  }
  __syncthreads();
  {
    const int l = t & 31, hh = t >> 5;
    float Sv = S_lds[l][hh];
    float mx = Sv;
#pragma unroll
    for (int m = 16; m >= 1; m >>= 1) mx = fmaxf(mx, __shfl_xor(mx, m, 32));
    float pr = __expf(Sv - mx);
    float su = pr;
#pragma unroll
    for (int m = 16; m >= 1; m >>= 1) su += __shfl_xor(su, m, 32);
    P_g[((long)b * 2 + (self ? 0 : 1)) * 256 + l * 8 + hh] = pr / su;
  }
  if (self) {
    const float* Kb = memK + (long)b * H + 4 * t;
    f32x4 a = {};
#pragma unroll
    for (int l = 0; l < 31; ++l) a += *(const f32x4*)(Kb + (long)(l + 1) * NB * H);
    a += *(const f32x4*)(hl + (long)b * H + 4 * t);
    *(f32x4*)(ts + (long)b * H + 4 * t) = a * (1.f / 32.f);
  }
}

// ---------------------------------------------------------------------------
// Attention V-mix (unchanged from round 11).
// ---------------------------------------------------------------------------
__global__ __launch_bounds__(256) void mix8_k(
    const float* __restrict__ memV, const float* __restrict__ extV,
    const float* __restrict__ hl,
    const float* __restrict__ P_g,
    unsigned short* __restrict__ mixS, unsigned short* __restrict__ mixE) {
  const int NB = 2048, H = 1024;
  __shared__ float P_lds[256];
  unsigned flat = blockIdx.x + gridDim.x * blockIdx.y;
  flat = (flat & 7u) * 512u + (flat >> 3);
  const int b = flat & 2047;
  const bool self = (flat >> 11) == 0;
  const int t = threadIdx.x;

  P_lds[t] = P_g[((long)b * 2 + (self ? 0 : 1)) * 256 + t];
  __syncthreads();

  const float* Vbase = (self ? memV + (long)NB * H : extV) + (long)b * H + 4 * t;
  const float* hlp = hl + (long)b * H + 4 * t;
  f32x4 acc[8] = {};
#pragma unroll
  for (int l = 0; l < 32; l += 2) {
    f32x4 vv0 = *(const f32x4*)(Vbase + (long)l * NB * H);
    f32x4 vv1 = *(const f32x4*)((self && l + 1 == 31) ? hlp
                                                      : Vbase + (long)(l + 1) * NB * H);
    const float* Pl0 = &P_lds[l * 8];
    const float* Pl1 = &P_lds[(l + 1) * 8];
#pragma unroll
    for (int hh = 0; hh < 8; ++hh) acc[hh] += Pl0[hh] * vv0;
#pragma unroll
    for (int hh = 0; hh < 8; ++hh) acc[hh] += Pl1[hh] * vv1;
  }
  unsigned short* mixp = (self ? mixS : mixE) + (long)b * 8192;
#pragma unroll
  for (int hh = 0; hh < 8; ++hh) {
    u16x4 pk;
    pk[0] = f2bf(acc[hh][0]); pk[1] = f2bf(acc[hh][1]);
    pk[2] = f2bf(acc[hh][2]); pk[3] = f2bf(acc[hh][3]);
    *(u16x4*)(mixp + hh * 1024 + 4 * t) = pk;
  }
}

extern "C" void kernel_launch(void* const* d_in, const int* in_sizes, int n_in,
                              void* d_out, int out_size, void* d_ws, size_t ws_size,
                              hipStream_t stream) {
  const float* x    = (const float*)d_in[0];
  const float* h    = (const float*)d_in[1];
  const float* c    = (const float*)d_in[2];
  const float* memK = (const float*)d_in[3];
  const float* memV = (const float*)d_in[4];
  const float* extK = (const float*)d_in[5];
  const float* extV = (const float*)d_in[6];
  const float* W_ih = (const float*)d_in[7];
  const float* W_hh = (const float*)d_in[8];
  const float* b_ih = (const float*)d_in[9];
  const float* b_hh = (const float*)d_in[10];
  const float* sWq = (const float*)d_in[11];
  const float* sbq = (const float*)d_in[12];
  const float* sWk = (const float*)d_in[13];
  const float* sWv = (const float*)d_in[15];
  const float* sbv = (const float*)d_in[16];
  const float* sWo = (const float*)d_in[17];
  const float* sbo = (const float*)d_in[18];
  const float* cWq = (const float*)d_in[19];
  const float* cbq = (const float*)d_in[20];
  const float* cWk = (const float*)d_in[21];
  const float* cWv = (const float*)d_in[23];
  const float* cbv = (const float*)d_in[24];
  const float* cWo = (const float*)d_in[25];
  const float* cbo = (const float*)d_in[26];
  const float* Wres = (const float*)d_in[27];
  const float* bres = (const float*)d_in[28];
  const float* Wrout = (const float*)d_in[29];
  const float* brout = (const float*)d_in[30];
  const float* Wcomp = (const float*)d_in[31];
  const float* bcomp = (const float*)d_in[32];
  const float* Wexp = (const float*)d_in[33];
  const float* bexp = (const float*)d_in[34];
  const float* Wgate = (const float*)d_in[35];
  const float* bgate = (const float*)d_in[36];
  (void)in_sizes; (void)n_in; (void)out_size; (void)ws_size;

  float* out = (float*)d_out;
  float* w = (float*)d_ws;
  const long M1 = 1024 * 1024;
  const long U = 1024 * 1024;  // u16 units
  unsigned short* ub = (unsigned short*)w;

  float* gates   = w;            // [2048,4096] f32 ; dead after lstm_k
  float* P_g     = w;            // [2048,2,256] f32 reuses gates
  float* hl      = w + 8 * M1;   // [2048,1024] f32
  unsigned short* qsS = (unsigned short*)(w + 10 * M1);  // [2048,1024] bf16
  unsigned short* qsE = (unsigned short*)(w + 12 * M1);
  unsigned short* qtS = (unsigned short*)(w + 16 * M1);  // f32 16-24M
  unsigned short* qtE = (unsigned short*)(w + 32 * M1);  // f32 32-40M
  unsigned short* mixS = (unsigned short*)(w + 48 * M1); // f32 48-56M
  unsigned short* mixE = (unsigned short*)(w + 64 * M1); // f32 64-72M
  float* ts      = w + 80 * M1;
  unsigned short* attnS = (unsigned short*)(w + 82 * M1);
  unsigned short* attnE = (unsigned short*)(w + 84 * M1);
  float* rw      = w + 90 * M1;
  float* rattn   = w + 91 * M1;
  float* routed  = w + 93 * M1;
  float* comp    = w + 95 * M1;
  float* expd    = w + 96 * M1;

  // bf16 buffers in proven-dead holes (f32 24-32M and 40-46.5M)
  unsigned short* Wihb  = ub + 48 * U;
  unsigned short* Whhb  = ub + 52 * U;
  unsigned short* xb    = ub + 56 * U;
  unsigned short* hb    = ub + 58 * U;
  unsigned short* sWqb  = ub + 60 * U;
  unsigned short* cWqb  = ub + 61 * U;
  unsigned short* sWvb  = ub + 62 * U;
  unsigned short* cWvb  = ub + 63 * U;
  unsigned short* sWob  = ub + 80 * U;
  unsigned short* cWob  = ub + 81 * U;
  unsigned short* Wresb = ub + 82 * U;
  unsigned short* Wcompb= ub + 83 * U;
  unsigned short* Wexpb = ub + 84 * U;
  unsigned short* Wgateb= ub + 85 * U;
  unsigned short* wkTsb = ub + 87 * U;
  unsigned short* wkTcb = ub + 88 * U;
  unsigned short* hlb   = ub + 89 * U;
  unsigned short* routedb = ub + 91 * U;

  float* hFinal_out = out;
  float* hl_out     = out + 2 * M1;
  float* cn_out     = out + 4 * M1;

  const float scaleq = 0.08838834764831845f;
  const int ZBIG = 1 << 30;
  dim3 blk(256);
  const float* nf = nullptr;
  const void* nv = nullptr;

  CJobs jb;
  jb.j[0] = {x, xb, 1024};
  jb.j[1] = {h, hb, 1024};
  jb.j[2] = {W_ih, Wihb, 2048};
  jb.j[3] = {W_hh, Whhb, 2048};
  jb.j[4] = {sWq, sWqb, 512};
  jb.j[5] = {cWq, cWqb, 512};
  jb.j[6] = {sWv, sWvb, 512};
  jb.j[7] = {cWv, cWvb, 512};
  jb.j[8] = {sWo, sWob, 512};
  jb.j[9] = {cWo, cWob, 512};
  jb.j[10] = {Wres, Wresb, 512};
  jb.j[11] = {Wcomp, Wcompb, 128};
  jb.j[12] = {Wexp, Wexpb, 128};
  jb.j[13] = {Wgate, Wgateb, 1024};
  conv_k<<<11008, blk, 0, stream>>>(jb);

  transpose_k<<<dim3(16, 16, 2), blk, 0, stream>>>(sWk, wkTsb, cWk, wkTcb, 1024);

  // gates = x@W_ih^T + h@W_hh^T + b_ih + b_hh  (all-bf16 operands)
  gemm_k<128, 1, 1, 0, 1, 1, 0><<<dim3(32, 16, 1), blk, 0, stream>>>(
      xb, nv, 1024, 0, hb, 1024, 1024,
      Wihb, nv, 1024, 0, Whhb, 1024,
      b_ih, nf, 0, b_hh,
      gates, nullptr, 4096, 0,
      2048, ZBIG, 1.f, nf, nf, nf, nf);

  lstm_k<<<2048, blk, 0, stream>>>(gates, c, Wrout, brout, cn_out, hl, hl_out, hlb, rw);

  // qs (z=0 self, z=1 ext), scaled, all-bf16
  gemm_k<128, 0, 0, 0, 1, 1, 1><<<dim3(8, 16, 2), blk, 0, stream>>>(
      hlb, hlb, 1024, 0, nv, 0, 0,
      sWqb, cWqb, 1024, 0, nv, 0,
      sbq, cbq, 0, nf,
      qsS, qsE, 1024, 0,
      1024, 1, scaleq, nf, nf, nf, nf);

  // qt = qs @ wkT ; z: 0-7 self, 8-15 ext (all-bf16)
  gemm_k<128, 0, 0, 0, 1, 1, 1><<<dim3(8, 16, 16), blk, 0, stream>>>(
      qsS, qsE, 1024, 128, nv, 0, 0,
      wkTsb, wkTcb, 1024, 128, nv, 0,
      nf, nf, 0, nf,
      qtS, qtE, 8192, 1024,
      128, 8, 1.f, nf, nf, nf, nf);

  scores9_k<<<dim3(2048, 2), blk, 0, stream>>>(memK, extK, hl, qtS, qtE, P_g, ts);
  mix8_k<<<dim3(2048, 2), blk, 0, stream>>>(memV, extV, hl, P_g, mixS, mixE);

  // attn' = (mix@Wv_h^T + bv) * rw (all-bf16)
  gemm_k<64, 0, 0, 3, 1, 1, 1><<<dim3(2, 16, 16), blk, 0, stream>>>(
      mixS, mixE, 8192, 1024, nv, 0, 0,
      sWvb, cWvb, 1024, 131072, nv, 0,
      sbv, cbv, 128, nf,
      attnS, attnE, 1024, 128,
      1024, 8, 1.f, rw, nf, nf, nf);

  // rattn = [w0*attnS | w1*attnE] @ [sWo;cWo]^T + w0*sbo + w1*cbo
  gemm_k<64, 1, 1, 4, 1, 1, 0><<<dim3(16, 16, 1), blk, 0, stream>>>(
      attnS, nv, 1024, 0, attnE, 1024, 1024,
      sWob, nv, 1024, 0, cWob, 1024,
      nf, nf, 0, nf,
      rattn, nullptr, 1024, 0,
      2048, ZBIG, 1.f, sbo, cbo, rw, nf);

  // routed = h_lstm + rattn + rattn@Wres^T + bres (+ bf16 mirror)
  gemm_k<64, 0, 0, 1, 0, 1, 0><<<dim3(16, 16, 1), blk, 0, stream>>>(
      rattn, nv, 1024, 0, nv, 0, 0,
      Wresb, nv, 1024, 0, nv, 0,
      bres, nf, 0, nf,
      routed, routedb, 1024, 0,
      1024, ZBIG, 1.f, hl, rattn, nf, nf);

  // compressed / expanded
  gemm_k<64, 0, 0, 0, 0, 1, 0><<<dim3(4, 16, 1), blk, 0, stream>>>(
      ts, nv, 1024, 0, nv, 0, 0,
      Wcompb, nv, 1024, 0, nv, 0,
      bcomp, nf, 0, nf,
      comp, nullptr, 256, 0,
      1024, ZBIG, 1.f, nf, nf, nf, nf);
  gemm_k<64, 0, 0, 0, 0, 1, 0><<<dim3(16, 16, 1), blk, 0, stream>>>(
      comp, nv, 256, 0, nv, 0, 0,
      Wexpb, nv, 256, 0, nv, 0,
      bexp, nf, 0, nf,
      expd, nullptr, 1024, 0,
      256, ZBIG, 1.f, nf, nf, nf, nf);

  // gate GEMM (A = [xb | routedb], all bf16) + fused final epilogue
  gemm_k<64, 1, 0, 2, 1, 1, 0><<<dim3(16, 16, 1), blk, 0, stream>>>(
      xb, nv, 1024, 0, routedb, 1024, 1024,
      Wgateb, nv, 2048, 0, nv, 0,
      bgate, nf, 0, nf,
      hFinal_out, nullptr, 1024, 0,
      2048, ZBIG, 1.f, comp, expd, hl, routed);
}

// Round 13
// 659.662 us; speedup vs baseline: 1.1954x; 1.0018x over previous
//
#include <hip/hip_runtime.h>
#include <math.h>

typedef __attribute__((ext_vector_type(4))) float f32x4;
typedef __attribute__((ext_vector_type(8))) short bf16x8;
typedef __attribute__((ext_vector_type(4))) unsigned short u16x4;
typedef __attribute__((ext_vector_type(8))) unsigned short u16x8;

__device__ __forceinline__ unsigned short f2bf(float f) {
  unsigned u = __builtin_bit_cast(unsigned, f);
  u += 0x7fffu + ((u >> 16) & 1u);
  return (unsigned short)(u >> 16);
}
__device__ __forceinline__ float bf2f(unsigned short s) {
  return __builtin_bit_cast(float, (unsigned)s << 16);
}
__device__ __forceinline__ float sigmoidf_(float x) { return 1.f / (1.f + __expf(-x)); }

// ---------------------------------------------------------------------------
// Batched fp32 -> bf16 conversion. Each job converted in 2048-elem blocks.
// ---------------------------------------------------------------------------
struct CJob { const float* s; unsigned short* d; int nblk; };
struct CJobs { CJob j[14]; };

__global__ __launch_bounds__(256) void conv_k(CJobs jb) {
  int b = blockIdx.x;
  int i = 0;
  while (b >= jb.j[i].nblk) { b -= jb.j[i].nblk; ++i; }
  const long base = (long)b * 2048 + threadIdx.x * 8;
  f32x4 a = *(const f32x4*)(jb.j[i].s + base);
  f32x4 c = *(const f32x4*)(jb.j[i].s + base + 4);
  u16x8 o;
  o[0] = f2bf(a[0]); o[1] = f2bf(a[1]); o[2] = f2bf(a[2]); o[3] = f2bf(a[3]);
  o[4] = f2bf(c[0]); o[5] = f2bf(c[1]); o[6] = f2bf(c[2]); o[7] = f2bf(c[3]);
  *(u16x8*)(jb.j[i].d + base) = o;
}

// ---------------------------------------------------------------------------
// bf16-MFMA GEMM, 128xTN tile (TN=128 or 64), BK=32, 4 waves, double-buffered
// LDS + 1-deep register prefetch, bijective XCD swizzle (grid product %8==0).
// C[M,N] = A[M,K] @ B[N,K]^T (+bias).
// ACAT/BCAT: K-concat. z-split: z>=zs -> "b" pointer set.
// ABF16/BBF16: operand dtype. OBF16: C bf16 (EPI 0/3).
// EPI 0: val*scale ; 1: val+P0+P1 (f32 C; if Cb, also bf16 mirror to Cb)
// EPI 2: (P2+P3+ce+sig(val)*(P1-ce))/3, ce=P0[row*256+(col&255)]
// EPI 3: val*P0[2*row+hi] (bf16) ; EPI 4: val+P2[2*row]*P0[col]+P2[2*row+1]*P1[col]
// ---------------------------------------------------------------------------
template <int TN, int ACAT, int BCAT, int EPI, int ABF16, int BBF16, int OBF16>
__global__ __launch_bounds__(256) void gemm_k(
    const void* __restrict__ A1, const void* __restrict__ A1b, int lda1, long aZ,
    const void* __restrict__ A2, int lda2, int Ksplit,
    const void* __restrict__ B1, const void* __restrict__ B1b, int ldb1, long bZ,
    const void* __restrict__ B2, int ldb2,
    const float* __restrict__ bias1, const float* __restrict__ bias1b, long biasZ,
    const float* __restrict__ bias2,
    void* __restrict__ C, void* __restrict__ Cb, int ldc, long cZ,
    int K, int zs, float scale,
    const float* __restrict__ P0, const float* __restrict__ P1,
    const float* __restrict__ P2, const float* __restrict__ P3) {
  constexpr int NBI = TN / 32;
  __shared__ unsigned short As[2][128][32];
  __shared__ unsigned short Bs[2][TN][32];
  const int t = threadIdx.x;
  const int lane = t & 63;
  const int wave = t >> 6;
  const int wr = wave >> 1, wc = wave & 1;

  const unsigned gx = gridDim.x, gy = gridDim.y;
  unsigned L = blockIdx.x + gx * (blockIdx.y + gy * blockIdx.z);
  const unsigned nwg = gx * gy * gridDim.z;
  L = (L & 7u) * (nwg >> 3) + (L >> 3);
  const int bn = L % gx;
  const unsigned r1 = L / gx;
  const int bm = r1 % gy;
  const int z = r1 / gy;

  const bool hi = z >= zs;
  const int zz = hi ? z - zs : z;
  const char* Abase = (const char*)(hi ? A1b : A1) + (long)zz * aZ * (ABF16 ? 2 : 4);
  const char* Bbase = (const char*)(hi ? B1b : B1) + (long)zz * bZ * (BBF16 ? 2 : 4);
  const float* biasp = hi ? bias1b : bias1;
  char* Czc = (char*)(hi ? Cb : C) + (long)zz * cZ * (OBF16 ? 2 : 4);

  const int ar = t >> 3;
  const int bc = (t & 7) * 4;

  const int kIters = K >> 5;
  u16x4 Ra[4], Rb[NBI];

  auto loadT = [&](int kt) {
    const int k0 = kt << 5;
    const char* Ap; int ldA, kA;
    if (ACAT == 1 && k0 >= Ksplit) { Ap = (const char*)A2; ldA = lda2; kA = k0 - Ksplit; }
    else { Ap = Abase; ldA = lda1; kA = k0; }
    const char* Bp; int ldB, kB;
    if (BCAT == 1 && k0 >= Ksplit) { Bp = (const char*)B2; ldB = ldb2; kB = k0 - Ksplit; }
    else { Bp = Bbase; ldB = ldb1; kB = k0; }
#pragma unroll
    for (int i = 0; i < 4; ++i) {
      const long aoff = ((long)bm * 128 + ar + 32 * i) * ldA + kA + bc;
      if (ABF16) {
        Ra[i] = *(const u16x4*)((const unsigned short*)Ap + aoff);
      } else {
        f32x4 v = *(const f32x4*)((const float*)Ap + aoff);
        u16x4 pk;
        pk[0] = f2bf(v[0]); pk[1] = f2bf(v[1]); pk[2] = f2bf(v[2]); pk[3] = f2bf(v[3]);
        Ra[i] = pk;
      }
    }
#pragma unroll
    for (int i = 0; i < NBI; ++i) {
      const long boff = ((long)bn * TN + ar + 32 * i) * ldB + kB + bc;
      if (BBF16) {
        Rb[i] = *(const u16x4*)((const unsigned short*)Bp + boff);
      } else {
        f32x4 bv = *(const f32x4*)((const float*)Bp + boff);
        u16x4 bp;
        bp[0] = f2bf(bv[0]); bp[1] = f2bf(bv[1]); bp[2] = f2bf(bv[2]); bp[3] = f2bf(bv[3]);
        Rb[i] = bp;
      }
    }
  };

  loadT(0);

  f32x4 acc[4][NBI] = {};
  int p = 0;
  for (int kt = 0; kt < kIters; ++kt) {
    __syncthreads();
#pragma unroll
    for (int i = 0; i < 4; ++i) *(u16x4*)&As[p][ar + 32 * i][bc] = Ra[i];
#pragma unroll
    for (int i = 0; i < NBI; ++i) *(u16x4*)&Bs[p][ar + 32 * i][bc] = Rb[i];
    if (kt + 1 < kIters) loadT(kt + 1);
    __syncthreads();

    bf16x8 af[4], bfr[NBI];
#pragma unroll
    for (int mi = 0; mi < 4; ++mi)
      af[mi] = *(const bf16x8*)&As[p][wr * 64 + mi * 16 + (lane & 15)][(lane >> 4) * 8];
#pragma unroll
    for (int ni = 0; ni < NBI; ++ni)
      bfr[ni] = *(const bf16x8*)&Bs[p][wc * (TN / 2) + ni * 16 + (lane & 15)][(lane >> 4) * 8];
#pragma unroll
    for (int mi = 0; mi < 4; ++mi)
#pragma unroll
      for (int ni = 0; ni < NBI; ++ni)
        acc[mi][ni] = __builtin_amdgcn_mfma_f32_16x16x32_bf16(af[mi], bfr[ni], acc[mi][ni], 0, 0, 0);
    p ^= 1;
  }

  const int colb = bn * TN + wc * (TN / 2);
  const int rowb = bm * 128 + wr * 64;
#pragma unroll
  for (int mi = 0; mi < 4; ++mi) {
#pragma unroll
    for (int ni = 0; ni < NBI; ++ni) {
      f32x4 v = acc[mi][ni];
      const int col = colb + ni * 16 + (lane & 15);
      const int row0 = rowb + mi * 16 + ((lane >> 4) << 2);
      float bsum = 0.f;
      if (biasp) bsum += biasp[zz * biasZ + col];
      if (bias2) bsum += bias2[col];
#pragma unroll
      for (int q = 0; q < 4; ++q) {
        const long row = row0 + q;
        const long off = row * ldc + col;
        const float val = v[q] + bsum;
        if (EPI == 0) {
          if (OBF16) ((unsigned short*)Czc)[off] = f2bf(val * scale);
          else       ((float*)Czc)[off] = val * scale;
        } else if (EPI == 1) {
          const float r2 = val + P0[off] + P1[off];
          ((float*)Czc)[off] = r2;
          if (Cb) ((unsigned short*)Cb)[off] = f2bf(r2);
        } else if (EPI == 2) {
          const float g = sigmoidf_(val);
          const float ce = P0[row * 256 + (col & 255)];
          const float ex = P1[off];
          ((float*)Czc)[off] = (P2[off] + P3[off] + ce + g * (ex - ce)) * (1.f / 3.f);
        } else if (EPI == 3) {
          ((unsigned short*)Czc)[off] = f2bf(val * P0[2 * row + (hi ? 1 : 0)]);
        } else {
          ((float*)Czc)[off] = val + P2[2 * row] * P0[col] + P2[2 * row + 1] * P1[col];
        }
      }
    }
  }
}

// 64x64 LDS-tiled transpose, f32 in -> bf16 out. out[n][d] = bf16(in[d][n])
__global__ __launch_bounds__(256) void transpose_k(const float* __restrict__ in0,
                                                   unsigned short* __restrict__ out0,
                                                   const float* __restrict__ in1,
                                                   unsigned short* __restrict__ out1, int n) {
  __shared__ float tile[64][65];
  const float* in = blockIdx.z ? in1 : in0;
  unsigned short* out = blockIdx.z ? out1 : out0;
  const int tr = blockIdx.y, tc = blockIdx.x, t = threadIdx.x;
#pragma unroll
  for (int it = 0; it < 16; ++it) {
    int idx = t + 256 * it;
    int r = idx >> 6, c = idx & 63;
    tile[r][c] = in[(long)(tr * 64 + r) * n + tc * 64 + c];
  }
  __syncthreads();
#pragma unroll
  for (int it = 0; it < 16; ++it) {
    int idx = t + 256 * it;
    int rr = idx >> 6, cc = idx & 63;
    out[(long)(tc * 64 + rr) * n + tr * 64 + cc] = f2bf(tile[cc][rr]);
  }
}

// LSTM elementwise + fused router; emits hl in f32 (ws+out) and bf16 (hlb)
__global__ __launch_bounds__(256) void lstm_k(const float* __restrict__ gates,
                                              const float* __restrict__ c_in,
                                              const float* __restrict__ Wr,
                                              const float* __restrict__ br,
                                              float* __restrict__ c_out,
                                              float* __restrict__ h_ws,
                                              float* __restrict__ h_out,
                                              unsigned short* __restrict__ hlb,
                                              float* __restrict__ rw) {
  const int b = blockIdx.x, t = threadIdx.x;
  const long base = (long)b * 1024 + t * 4;
  const float* gb = gates + (long)b * 4096 + t * 4;
  f32x4 gi = *(const f32x4*)(gb);
  f32x4 gf = *(const f32x4*)(gb + 1024);
  f32x4 gg = *(const f32x4*)(gb + 2048);
  f32x4 go = *(const f32x4*)(gb + 3072);
  f32x4 cv = *(const f32x4*)(c_in + base);
  f32x4 cn, hv;
#pragma unroll
  for (int q = 0; q < 4; ++q) {
    float cc = sigmoidf_(gf[q]) * cv[q] + sigmoidf_(gi[q]) * tanhf(gg[q]);
    cn[q] = cc;
    hv[q] = sigmoidf_(go[q]) * tanhf(cc);
  }
  *(f32x4*)(c_out + base) = cn;
  *(f32x4*)(h_ws + base) = hv;
  *(f32x4*)(h_out + base) = hv;
  u16x4 hp;
  hp[0] = f2bf(hv[0]); hp[1] = f2bf(hv[1]); hp[2] = f2bf(hv[2]); hp[3] = f2bf(hv[3]);
  *(u16x4*)(hlb + base) = hp;
  f32x4 w0 = *(const f32x4*)(Wr + t * 4);
  f32x4 w1 = *(const f32x4*)(Wr + 1024 + t * 4);
  float a0 = hv[0] * w0[0] + hv[1] * w0[1] + hv[2] * w0[2] + hv[3] * w0[3];
  float a1 = hv[0] * w1[0] + hv[1] * w1[1] + hv[2] * w1[2] + hv[3] * w1[3];
#pragma unroll
  for (int m = 32; m >= 1; m >>= 1) {
    a0 += __shfl_xor(a0, m);
    a1 += __shfl_xor(a1, m);
  }
  __shared__ float red[8];
  if ((t & 63) == 0) { red[t >> 6] = a0; red[4 + (t >> 6)] = a1; }
  __syncthreads();
  if (t == 0) {
    float z0 = red[0] + red[1] + red[2] + red[3] + br[0];
    float z1 = red[4] + red[5] + red[6] + red[7] + br[1];
    float mx = fmaxf(z0, z1);
    float e0 = __expf(z0 - mx), e1 = __expf(z1 - mx);
    float s = e0 + e1;
    rw[2 * b] = e0 / s;
    rw[2 * b + 1] = e1 / s;
  }
}

// ---------------------------------------------------------------------------
// FUSED attention: scores + softmax + ts + V-mix, block = one (b, side).
// Merges round-12's scores9_k and mix8_k (both lean) so each block starts
// streaming V right after ITS OWN softmax (no kernel-wide barrier, no P
// round-trip). LDS: qtf 36 KB + S 1 KB + P 1 KB -> 4 blocks/CU, ~72 VGPR.
// ---------------------------------------------------------------------------
__global__ __launch_bounds__(256) void attn10_k(
    const float* __restrict__ memK, const float* __restrict__ memV,
    const float* __restrict__ extK, const float* __restrict__ extV,
    const float* __restrict__ hl,
    const unsigned short* __restrict__ qtS, const unsigned short* __restrict__ qtE,
    unsigned short* __restrict__ mixS, unsigned short* __restrict__ mixE,
    float* __restrict__ ts) {
  const int NB = 2048, H = 1024;
  __shared__ float qtf[256 * 36];
  __shared__ float S_lds[32][8];
  __shared__ float P_lds[256];  // [l][h], h fastest
  unsigned flat = blockIdx.x + gridDim.x * blockIdx.y;
  flat = (flat & 7u) * 512u + (flat >> 3);  // bijective XCD swizzle
  const int b = flat & 2047;
  const bool self = (flat >> 11) == 0;
  const int t = threadIdx.x;

  // ---- stage qt: global [h][k] bf16 -> LDS [kq][h] f32x4 (pitch 36) ----
  {
    const unsigned short* qtb = (self ? qtS : qtE) + (long)b * 8192;
#pragma unroll
    for (int i = 0; i < 4; ++i) {
      const int chunk = t + 256 * i;
      const int hh = chunk >> 7;
      const int pos = (chunk & 127) * 8;
      u16x8 qv = *(const u16x8*)(qtb + hh * 1024 + pos);
      const int kq0 = pos >> 2;
      f32x4 a, bb;
      a[0] = bf2f(qv[0]); a[1] = bf2f(qv[1]); a[2] = bf2f(qv[2]); a[3] = bf2f(qv[3]);
      bb[0] = bf2f(qv[4]); bb[1] = bf2f(qv[5]); bb[2] = bf2f(qv[6]); bb[3] = bf2f(qv[7]);
      *(f32x4*)&qtf[kq0 * 36 + hh * 4] = a;
      *(f32x4*)&qtf[(kq0 + 1) * 36 + hh * 4] = bb;
    }
  }
  __syncthreads();

  // ---- K phase: scores (lane owns row r = t>>3, 128B slice sub = t&7) ----
  const int r = t >> 3, sub = t & 7;
  const float* Kr = self ? ((r < 31) ? memK + ((long)(r + 1) * NB + b) * H : hl + (long)b * H)
                         : extK + ((long)r * NB + b) * H;
  float acc[8] = {};
#pragma unroll
  for (int i = 0; i < 32; i += 4) {
    f32x4 kv[4];
#pragma unroll
    for (int u = 0; u < 4; ++u) kv[u] = *(const f32x4*)(Kr + ((i + u) * 8 + sub) * 4);
#pragma unroll
    for (int u = 0; u < 4; ++u) {
      const float* qp = &qtf[((i + u) * 8 + sub) * 36];
#pragma unroll
      for (int hh = 0; hh < 8; ++hh) {
        f32x4 q = *(const f32x4*)(qp + hh * 4);
        acc[hh] += kv[u][0] * q[0] + kv[u][1] * q[1] + kv[u][2] * q[2] + kv[u][3] * q[3];
      }
    }
  }
#pragma unroll
  for (int hh = 0; hh < 8; ++hh) {
    acc[hh] += __shfl_xor(acc[hh], 1);
    acc[hh] += __shfl_xor(acc[hh], 2);
    acc[hh] += __shfl_xor(acc[hh], 4);
  }
  if (sub == 0) {
#pragma unroll
    for (int hh = 0; hh < 8; ++hh) S_lds[r][hh] = acc[hh];
  }
  __syncthreads();

  // ---- softmax over l per head; P -> LDS ----
  {
    const int l = t & 31, hh = t >> 5;
    float Sv = S_lds[l][hh];
    float mx = Sv;
#pragma unroll
    for (int m = 16; m >= 1; m >>= 1) mx = fmaxf(mx, __shfl_xor(mx, m, 32));
    float pr = __expf(Sv - mx);
    float su = pr;
#pragma unroll
    for (int m = 16; m >= 1; m >>= 1) su += __shfl_xor(su, m, 32);
    P_lds[l * 8 + hh] = pr / su;
  }

  // ---- ts (self): column means, coalesced L2/L3-warm re-read ----
  if (self) {
    const float* Kb = memK + (long)b * H + 4 * t;
    f32x4 a = {};
#pragma unroll
    for (int l = 0; l < 31; ++l) a += *(const f32x4*)(Kb + (long)(l + 1) * NB * H);
    a += *(const f32x4*)(hl + (long)b * H + 4 * t);
    *(f32x4*)(ts + (long)b * H + 4 * t) = a * (1.f / 32.f);
  }
  __syncthreads();  // P_lds visible

  // ---- V phase: mix[h][d] = sum_l P[l][h] * V[l][d] ----
  const float* Vbase = (self ? memV + (long)NB * H : extV) + (long)b * H + 4 * t;
  const float* hlp = hl + (long)b * H + 4 * t;
  f32x4 vacc[8] = {};
#pragma unroll
  for (int l = 0; l < 32; l += 2) {
    f32x4 vv0 = *(const f32x4*)(Vbase + (long)l * NB * H);
    f32x4 vv1 = *(const f32x4*)((self && l + 1 == 31) ? hlp
                                                      : Vbase + (long)(l + 1) * NB * H);
    const float* Pl0 = &P_lds[l * 8];
    const float* Pl1 = &P_lds[(l + 1) * 8];
#pragma unroll
    for (int hh = 0; hh < 8; ++hh) vacc[hh] += Pl0[hh] * vv0;
#pragma unroll
    for (int hh = 0; hh < 8; ++hh) vacc[hh] += Pl1[hh] * vv1;
  }
  unsigned short* mixp = (self ? mixS : mixE) + (long)b * 8192;
#pragma unroll
  for (int hh = 0; hh < 8; ++hh) {
    u16x4 pk;
    pk[0] = f2bf(vacc[hh][0]); pk[1] = f2bf(vacc[hh][1]);
    pk[2] = f2bf(vacc[hh][2]); pk[3] = f2bf(vacc[hh][3]);
    *(u16x4*)(mixp + hh * 1024 + 4 * t) = pk;
  }
}

extern "C" void kernel_launch(void* const* d_in, const int* in_sizes, int n_in,
                              void* d_out, int out_size, void* d_ws, size_t ws_size,
                              hipStream_t stream) {
  const float* x    = (const float*)d_in[0];
  const float* h    = (const float*)d_in[1];
  const float* c    = (const float*)d_in[2];
  const float* memK = (const float*)d_in[3];
  const float* memV = (const float*)d_in[4];
  const float* extK = (const float*)d_in[5];
  const float* extV = (const float*)d_in[6];
  const float* W_ih = (const float*)d_in[7];
  const float* W_hh = (const float*)d_in[8];
  const float* b_ih = (const float*)d_in[9];
  const float* b_hh = (const float*)d_in[10];
  const float* sWq = (const float*)d_in[11];
  const float* sbq = (const float*)d_in[12];
  const float* sWk = (const float*)d_in[13];
  const float* sWv = (const float*)d_in[15];
  const float* sbv = (const float*)d_in[16];
  const float* sWo = (const float*)d_in[17];
  const float* sbo = (const float*)d_in[18];
  const float* cWq = (const float*)d_in[19];
  const float* cbq = (const float*)d_in[20];
  const float* cWk = (const float*)d_in[21];
  const float* cWv = (const float*)d_in[23];
  const float* cbv = (const float*)d_in[24];
  const float* cWo = (const float*)d_in[25];
  const float* cbo = (const float*)d_in[26];
  const float* Wres = (const float*)d_in[27];
  const float* bres = (const float*)d_in[28];
  const float* Wrout = (const float*)d_in[29];
  const float* brout = (const float*)d_in[30];
  const float* Wcomp = (const float*)d_in[31];
  const float* bcomp = (const float*)d_in[32];
  const float* Wexp = (const float*)d_in[33];
  const float* bexp = (const float*)d_in[34];
  const float* Wgate = (const float*)d_in[35];
  const float* bgate = (const float*)d_in[36];
  (void)in_sizes; (void)n_in; (void)out_size; (void)ws_size;

  float* out = (float*)d_out;
  float* w = (float*)d_ws;
  const long M1 = 1024 * 1024;
  const long U = 1024 * 1024;  // u16 units
  unsigned short* ub = (unsigned short*)w;

  float* gates   = w;            // [2048,4096] f32 ; dead after lstm_k
  float* hl      = w + 8 * M1;   // [2048,1024] f32
  unsigned short* qsS = (unsigned short*)(w + 10 * M1);
  unsigned short* qsE = (unsigned short*)(w + 12 * M1);
  unsigned short* qtS = (unsigned short*)(w + 16 * M1);  // f32 16-24M
  unsigned short* qtE = (unsigned short*)(w + 32 * M1);  // f32 32-40M
  unsigned short* mixS = (unsigned short*)(w + 48 * M1); // f32 48-56M
  unsigned short* mixE = (unsigned short*)(w + 64 * M1); // f32 64-72M
  float* ts      = w + 80 * M1;
  unsigned short* attnS = (unsigned short*)(w + 82 * M1);
  unsigned short* attnE = (unsigned short*)(w + 84 * M1);
  float* rw      = w + 90 * M1;
  float* rattn   = w + 91 * M1;
  float* routed  = w + 93 * M1;
  float* comp    = w + 95 * M1;
  float* expd    = w + 96 * M1;

  // bf16 buffers in proven-dead holes (f32 24-32M and 40-46.5M)
  unsigned short* Wihb  = ub + 48 * U;
  unsigned short* Whhb  = ub + 52 * U;
  unsigned short* xb    = ub + 56 * U;
  unsigned short* hb    = ub + 58 * U;
  unsigned short* sWqb  = ub + 60 * U;
  unsigned short* cWqb  = ub + 61 * U;
  unsigned short* sWvb  = ub + 62 * U;
  unsigned short* cWvb  = ub + 63 * U;
  unsigned short* sWob  = ub + 80 * U;
  unsigned short* cWob  = ub + 81 * U;
  unsigned short* Wresb = ub + 82 * U;
  unsigned short* Wcompb= ub + 83 * U;
  unsigned short* Wexpb = ub + 84 * U;
  unsigned short* Wgateb= ub + 85 * U;
  unsigned short* wkTsb = ub + 87 * U;
  unsigned short* wkTcb = ub + 88 * U;
  unsigned short* hlb   = ub + 89 * U;
  unsigned short* routedb = ub + 91 * U;

  float* hFinal_out = out;
  float* hl_out     = out + 2 * M1;
  float* cn_out     = out + 4 * M1;

  const float scaleq = 0.08838834764831845f;
  const int ZBIG = 1 << 30;
  dim3 blk(256);
  const float* nf = nullptr;
  const void* nv = nullptr;

  CJobs jb;
  jb.j[0] = {x, xb, 1024};
  jb.j[1] = {h, hb, 1024};
  jb.j[2] = {W_ih, Wihb, 2048};
  jb.j[3] = {W_hh, Whhb, 2048};
  jb.j[4] = {sWq, sWqb, 512};
  jb.j[5] = {cWq, cWqb, 512};
  jb.j[6] = {sWv, sWvb, 512};
  jb.j[7] = {cWv, cWvb, 512};
  jb.j[8] = {sWo, sWob, 512};
  jb.j[9] = {cWo, cWob, 512};
  jb.j[10] = {Wres, Wresb, 512};
  jb.j[11] = {Wcomp, Wcompb, 128};
  jb.j[12] = {Wexp, Wexpb, 128};
  jb.j[13] = {Wgate, Wgateb, 1024};
  conv_k<<<11008, blk, 0, stream>>>(jb);

  transpose_k<<<dim3(16, 16, 2), blk, 0, stream>>>(sWk, wkTsb, cWk, wkTcb, 1024);

  // gates = x@W_ih^T + h@W_hh^T + b_ih + b_hh  (all-bf16 operands)
  gemm_k<128, 1, 1, 0, 1, 1, 0><<<dim3(32, 16, 1), blk, 0, stream>>>(
      xb, nv, 1024, 0, hb, 1024, 1024,
      Wihb, nv, 1024, 0, Whhb, 1024,
      b_ih, nf, 0, b_hh,
      gates, nullptr, 4096, 0,
      2048, ZBIG, 1.f, nf, nf, nf, nf);

  lstm_k<<<2048, blk, 0, stream>>>(gates, c, Wrout, brout, cn_out, hl, hl_out, hlb, rw);

  // qs (z=0 self, z=1 ext), scaled, all-bf16
  gemm_k<128, 0, 0, 0, 1, 1, 1><<<dim3(8, 16, 2), blk, 0, stream>>>(
      hlb, hlb, 1024, 0, nv, 0, 0,
      sWqb, cWqb, 1024, 0, nv, 0,
      sbq, cbq, 0, nf,
      qsS, qsE, 1024, 0,
      1024, 1, scaleq, nf, nf, nf, nf);

  // qt = qs @ wkT ; z: 0-7 self, 8-15 ext (all-bf16)
  gemm_k<128, 0, 0, 0, 1, 1, 1><<<dim3(8, 16, 16), blk, 0, stream>>>(
      qsS, qsE, 1024, 128, nv, 0, 0,
      wkTsb, wkTcb, 1024, 128, nv, 0,
      nf, nf, 0, nf,
      qtS, qtE, 8192, 1024,
      128, 8, 1.f, nf, nf, nf, nf);

  // fused attention (scores + softmax + ts + V-mix)
  attn10_k<<<dim3(2048, 2), blk, 0, stream>>>(memK, memV, extK, extV, hl,
                                              qtS, qtE, mixS, mixE, ts);

  // attn' = (mix@Wv_h^T + bv) * rw (all-bf16)
  gemm_k<64, 0, 0, 3, 1, 1, 1><<<dim3(2, 16, 16), blk, 0, stream>>>(
      mixS, mixE, 8192, 1024, nv, 0, 0,
      sWvb, cWvb, 1024, 131072, nv, 0,
      sbv, cbv, 128, nf,
      attnS, attnE, 1024, 128,
      1024, 8, 1.f, rw, nf, nf, nf);

  // rattn = [w0*attnS | w1*attnE] @ [sWo;cWo]^T + w0*sbo + w1*cbo
  gemm_k<64, 1, 1, 4, 1, 1, 0><<<dim3(16, 16, 1), blk, 0, stream>>>(
      attnS, nv, 1024, 0, attnE, 1024, 1024,
      sWob, nv, 1024, 0, cWob, 1024,
      nf, nf, 0, nf,
      rattn, nullptr, 1024, 0,
      2048, ZBIG, 1.f, sbo, cbo, rw, nf);

  // routed = h_lstm + rattn + rattn@Wres^T + bres (+ bf16 mirror)
  gemm_k<64, 0, 0, 1, 0, 1, 0><<<dim3(16, 16, 1), blk, 0, stream>>>(
      rattn, nv, 1024, 0, nv, 0, 0,
      Wresb, nv, 1024, 0, nv, 0,
      bres, nf, 0, nf,
      routed, routedb, 1024, 0,
      1024, ZBIG, 1.f, hl, rattn, nf, nf);

  // compressed / expanded
  gemm_k<64, 0, 0, 0, 0, 1, 0><<<dim3(4, 16, 1), blk, 0, stream>>>(
      ts, nv, 1024, 0, nv, 0, 0,
      Wcompb, nv, 1024, 0, nv, 0,
      bcomp, nf, 0, nf,
      comp, nullptr, 256, 0,
      1024, ZBIG, 1.f, nf, nf, nf, nf);
  gemm_k<64, 0, 0, 0, 0, 1, 0><<<dim3(16, 16, 1), blk, 0, stream>>>(
      comp, nv, 256, 0, nv, 0, 0,
      Wexpb, nv, 256, 0, nv, 0,
      bexp, nf, 0, nf,
      expd, nullptr, 1024, 0,
      256, ZBIG, 1.f, nf, nf, nf, nf);

  // gate GEMM (A = [xb | routedb], all bf16) + fused final epilogue
  gemm_k<64, 1, 0, 2, 1, 1, 0><<<dim3(16, 16, 1), blk, 0, stream>>>(
      xb, nv, 1024, 0, routedb, 1024, 1024,
      Wgateb, nv, 2048, 0, nv, 0,
      bgate, nf, 0, nf,
      hFinal_out, nullptr, 1024, 0,
      2048, ZBIG, 1.f, comp, expd, hl, routed);
}